// Round 1
// baseline (465.269 us; speedup 1.0000x reference)
//
#include <hip/hip_runtime.h>

// NCC dual-force 3D: 256^3 fp32 volumes.
// Plane-marching separable box-sum: block = (64 x-lanes, 8 y-rows), each
// thread walks a 32-deep z-chunk. x+-1 neighbors via __shfl within the wave
// (lanes 0/63 are halo, outputs from lanes 1..62). No LDS, no syncthreads.

constexpr int DIM    = 256;
constexpr int PLANE  = DIM * DIM;        // 65536
constexpr int NVOX   = DIM * DIM * DIM;  // 16777216
constexpr int TILE_X = 62;               // outputs per wave (lanes 1..62)
constexpr int TILE_Y = 8;
constexpr int CHUNK_Z = 32;
constexpr float EPSF = 1e-6f;

__global__ __launch_bounds__(512) void ncc_forces(
    const float* __restrict__ M, const float* __restrict__ F,
    const int* __restrict__ maskM, const int* __restrict__ maskF,
    float* __restrict__ out)
{
    const int tx = threadIdx.x;                    // 0..63
    const int ty = threadIdx.y;                    // 0..7
    const int x  = blockIdx.x * TILE_X - 1 + tx;   // global x (may be -1 or >=DIM: halo)
    const int y  = blockIdx.y * TILE_Y + ty;       // always in [0,DIM)
    const int z0 = blockIdx.z * CHUNK_Z;

    const bool xok      = (unsigned)x < (unsigned)DIM;
    const bool do_store = (tx >= 1) && (tx <= TILE_X) && (x < DIM);
    const int laneL = (tx == 0)  ? 0  : tx - 1;    // clamped; lane 0/63 outputs unused
    const int laneR = (tx == 63) ? 63 : tx + 1;
    const bool yUok = (y - 1) >= 0;
    const bool yDok = (y + 1) < DIM;

    // z-rings: plane sums (3x3 in-plane window) for the 5 box-sum quantities
    float Pm0=0.f,Pf0=0.f,Pmm0=0.f,Pff0=0.f,Pmf0=0.f;
    float Pm1=0.f,Pf1=0.f,Pmm1=0.f,Pff1=0.f,Pmf1=0.f;
    // center-value ring (for mmc/fmc and gz) and previous-plane gx/gy
    float mcA=0.f, mcB=0.f, fcA=0.f, fcB=0.f;
    float gxm_p=0.f, gym_p=0.f, gxf_p=0.f, gyf_p=0.f;

    for (int s = 0; s <= CHUNK_Z + 1; ++s) {
        const int  zl  = z0 - 1 + s;               // plane being ingested
        const bool zok = (unsigned)zl < (unsigned)DIM;

        float mU=0.f, mC=0.f, mD=0.f, fU=0.f, fC=0.f, fD=0.f;
        if (zok && xok) {
            const int rowC = zl * PLANE + y * DIM + x;
            mC = M[rowC]; fC = F[rowC];
            if (yUok) { mU = M[rowC - DIM]; fU = F[rowC - DIM]; }
            if (yDok) { mD = M[rowC + DIM]; fD = F[rowC + DIM]; }
        }

        // x-neighbors via wave shuffles (zero-pad arrives naturally from halo lanes)
        const float mUL=__shfl(mU,laneL), mUR=__shfl(mU,laneR);
        const float mCL=__shfl(mC,laneL), mCR=__shfl(mC,laneR);
        const float mDL=__shfl(mD,laneL), mDR=__shfl(mD,laneR);
        const float fUL=__shfl(fU,laneL), fUR=__shfl(fU,laneR);
        const float fCL=__shfl(fC,laneL), fCR=__shfl(fC,laneR);
        const float fDL=__shfl(fD,laneL), fDR=__shfl(fD,laneR);

        // 3x3 in-plane sums of the five quantities at plane zl
        const float Pm2  = (mUL+mU+mUR)+(mCL+mC+mCR)+(mDL+mD+mDR);
        const float Pf2  = (fUL+fU+fUR)+(fCL+fC+fCR)+(fDL+fD+fDR);
        const float Pmm2 = (mUL*mUL+mU*mU+mUR*mUR)+(mCL*mCL+mC*mC+mCR*mCR)+(mDL*mDL+mD*mD+mDR*mDR);
        const float Pff2 = (fUL*fUL+fU*fU+fUR*fUR)+(fCL*fCL+fC*fC+fCR*fCR)+(fDL*fDL+fD*fD+fDR*fDR);
        const float Pmf2 = (mUL*fUL+mU*fU+mUR*fUR)+(mCL*fCL+mC*fC+mCR*fCR)+(mDL*fDL+mD*fD+mDR*fDR);

        // in-plane gradients at plane zl (torch.gradient boundary rules)
        const float gxm = (x==0) ? (mCR-mC) : (x==DIM-1) ? (mC-mCL) : 0.5f*(mCR-mCL);
        const float gxf = (x==0) ? (fCR-fC) : (x==DIM-1) ? (fC-fCL) : 0.5f*(fCR-fCL);
        const float gym = (y==0) ? (mD-mC) : (y==DIM-1) ? (mC-mU) : 0.5f*(mD-mU);
        const float gyf = (y==0) ? (fD-fC) : (y==DIM-1) ? (fC-fU) : 0.5f*(fD-fU);

        if (s >= 2 && do_store) {
            const int zo = zl - 1;                 // output plane

            const float sum_m  = Pm0  + Pm1  + Pm2;
            const float sum_f  = Pf0  + Pf1  + Pf2;
            const float sum_mm = Pmm0 + Pmm1 + Pmm2;
            const float sum_ff = Pff0 + Pff1 + Pff2;
            const float sum_mf = Pmf0 + Pmf1 + Pmf2;

            // replicate reference arithmetic exactly (fp32)
            const float moving_mean = sum_m / 27.0f;
            const float fixed_mean  = sum_f / 27.0f;
            const float var_m = sum_mm - 2.0f*moving_mean*sum_m + 27.0f*moving_mean*moving_mean;
            const float var_f = sum_ff - 2.0f*fixed_mean*sum_f  + 27.0f*fixed_mean*fixed_mean;
            const float var_mf = var_m * var_f;
            const float cross = sum_mf - fixed_mean*sum_m - moving_mean*sum_f
                                + 27.0f*moving_mean*fixed_mean;
            const float mmc = mcB - moving_mean;   // mcB = m at plane zo
            const float fmc = fcB - fixed_mean;
            const float factor = 2.0f * cross / (var_mf + EPSF)
                                 * (mmc - cross / (var_f * fmc + EPSF));

            // gz at zo from center ring: mcA=m(zo-1), mcB=m(zo), mC=m(zo+1)
            const float gzm = (zo==0) ? (mC - mcB) : (zo==DIM-1) ? (mcB - mcA) : 0.5f*(mC - mcA);
            const float gzf = (zo==0) ? (fC - fcB) : (zo==DIM-1) ? (fcB - fcA) : 0.5f*(fC - fcA);

            const int idx = zo * PLANE + y * DIM + x;
            const float wm = maskM[idx] ? 1.0f : 0.0f;
            const float wf = maskF[idx] ? 1.0f : 0.0f;

            const float tgz = 0.5f*(gzm  *wm + gzf  *wf);
            const float tgy = 0.5f*(gym_p*wm + gyf_p*wf);   // gx/gy computed last step (plane zo)
            const float tgx = 0.5f*(gxm_p*wm + gxf_p*wf);

            out[idx]          = -factor * tgz;   // channel 0: d/dz
            out[NVOX + idx]   = -factor * tgy;   // channel 1: d/dy
            out[2*NVOX + idx] = -factor * tgx;   // channel 2: d/dx
        }

        // shift rings
        Pm0=Pm1;  Pf0=Pf1;  Pmm0=Pmm1; Pff0=Pff1; Pmf0=Pmf1;
        Pm1=Pm2;  Pf1=Pf2;  Pmm1=Pmm2; Pff1=Pff2; Pmf1=Pmf2;
        mcA=mcB;  mcB=mC;   fcA=fcB;   fcB=fC;
        gxm_p=gxm; gym_p=gym; gxf_p=gxf; gyf_p=gyf;
    }
}

extern "C" void kernel_launch(void* const* d_in, const int* in_sizes, int n_in,
                              void* d_out, int out_size, void* d_ws, size_t ws_size,
                              hipStream_t stream) {
    const float* M  = (const float*)d_in[0];
    const float* F  = (const float*)d_in[1];
    const int* mm   = (const int*)d_in[2];
    const int* fm   = (const int*)d_in[3];
    float* out      = (float*)d_out;

    dim3 block(64, TILE_Y, 1);
    dim3 grid((DIM + TILE_X - 1) / TILE_X,   // 5 x-tiles (62 outputs each)
              DIM / TILE_Y,                  // 32
              DIM / CHUNK_Z);                // 8
    hipLaunchKernelGGL(ncc_forces, grid, block, 0, stream, M, F, mm, fm, out);
}

// Round 3
// 404.291 us; speedup vs baseline: 1.1508x; 1.1508x over previous
//
#include <hip/hip_runtime.h>

// NCC dual-force 3D, 256^3 fp32.
// One wave spans the FULL x-row: 64 lanes x 4 floats (float4) = 256.
// Separable 3x3x3 box sums: y-sum in registers, x-sum via 2 shuffles per
// quantity, z-sum via a 3-deep register ring (compile-time rotation under
// full unroll). 4 outputs per lane per plane-step. No LDS, no syncthreads.

constexpr int DIM     = 256;
constexpr int PLANE   = DIM * DIM;
constexpr int NVOX    = DIM * DIM * DIM;
constexpr int CHUNK_Z = 16;            // outputs per thread along z
constexpr int BY      = 4;             // waves per block (y rows)
constexpr float EPSF  = 1e-6f;

// native vector type for nontemporal 16B stores (HIP_vector_type is rejected
// by __builtin_nontemporal_store)
typedef float nvec4 __attribute__((ext_vector_type(4)));

__device__ __forceinline__ float shlz(float v) {   // lane l <- lane l-1; lane0 -> 0 (zero pad)
    float r = __shfl_up(v, 1);
    return (threadIdx.x == 0) ? 0.f : r;
}
__device__ __forceinline__ float shrz(float v) {   // lane l <- lane l+1; lane63 -> 0
    float r = __shfl_down(v, 1);
    return (threadIdx.x == 63) ? 0.f : r;
}
__device__ __forceinline__ float4 add3(const float4& a, const float4& b, const float4& c) {
    return make_float4(a.x+b.x+c.x, a.y+b.y+c.y, a.z+b.z+c.z, a.w+b.w+c.w);
}
__device__ __forceinline__ float4 prod3(const float4& a, const float4& b,
                                        const float4& c, const float4& d,
                                        const float4& e, const float4& f) {
    return make_float4(a.x*b.x + c.x*d.x + e.x*f.x,
                       a.y*b.y + c.y*d.y + e.y*f.y,
                       a.z*b.z + c.z*d.z + e.z*f.z,
                       a.w*b.w + c.w*d.w + e.w*f.w);
}
__device__ __forceinline__ float4 sub4(const float4& a, const float4& b) {
    return make_float4(a.x-b.x, a.y-b.y, a.z-b.z, a.w-b.w);
}
__device__ __forceinline__ float4 scl4(const float4& a, float s) {
    return make_float4(a.x*s, a.y*s, a.z*s, a.w*s);
}
// 3-wide x window sum of a per-element quantity; ends from neighbor lanes (zero-padded)
__device__ __forceinline__ float4 xsum3(const float4& c) {
    float l = shlz(c.w), r = shrz(c.x);
    return make_float4(l + c.x + c.y, c.x + c.y + c.z, c.y + c.z + c.w, c.z + c.w + r);
}
__device__ __forceinline__ void ntstore4(float* p, const float4& v) {
    nvec4 t; t.x = v.x; t.y = v.y; t.z = v.z; t.w = v.w;
    __builtin_nontemporal_store(t, (nvec4*)p);
}

// scalar pointwise NCC-force; arithmetic replicates the reference op-for-op
__device__ __forceinline__ void pw1(
    float sum_m, float sum_f, float sum_mm, float sum_ff, float sum_mf,
    float mA, float mB, float mN,   // m at planes zo-1, zo, zo+1
    float fA, float fB, float fN,
    int zflag,                      // -1: zo==0, +1: zo==DIM-1, 0: interior
    float gx_m, float gy_m, float gx_f, float gy_f,
    int km, int kf,
    float& o0, float& o1, float& o2)
{
    float mmean = sum_m / 27.0f;
    float fmean = sum_f / 27.0f;
    float var_m = sum_mm - 2.f*mmean*sum_m + 27.f*mmean*mmean;
    float var_f = sum_ff - 2.f*fmean*sum_f + 27.f*fmean*fmean;
    float cross = sum_mf - fmean*sum_m - mmean*sum_f + 27.f*mmean*fmean;
    float mmc = mB - mmean, fmc = fB - fmean;
    float factor = 2.f * cross / (var_m*var_f + EPSF)
                   * (mmc - cross / (var_f*fmc + EPSF));
    float gzm = (zflag < 0) ? (mN - mB) : ((zflag > 0) ? (mB - mA) : 0.5f*(mN - mA));
    float gzf = (zflag < 0) ? (fN - fB) : ((zflag > 0) ? (fB - fA) : 0.5f*(fN - fA));
    float wm = km ? 1.f : 0.f, wf = kf ? 1.f : 0.f;
    float nf = -0.5f * factor;
    o0 = nf * (gzm*wm + gzf*wf);
    o1 = nf * (gy_m*wm + gy_f*wf);
    o2 = nf * (gx_m*wm + gx_f*wf);
}

__global__ __launch_bounds__(64 * BY) void ncc_forces(
    const float* __restrict__ M, const float* __restrict__ F,
    const int* __restrict__ maskM, const int* __restrict__ maskF,
    float* __restrict__ out)
{
    const int y  = blockIdx.y * BY + threadIdx.y;
    const int z0 = blockIdx.z * CHUNK_Z;
    const int xb = threadIdx.x * 4;
    const bool yUok = (y > 0), yDok = (y < DIM - 1);

    float4 Pm[3], Pf[3], Pmm[3], Pff[3], Pmf[3];   // plane-sum z-ring
    float4 mc[3], fc[3];                           // center values z-ring
    float4 gxm_p, gym_p, gxf_p, gyf_p;             // in-plane grads at plane zo

    auto ingest = [&](int slot, int zl, float4& gxm, float4& gym, float4& gxf, float4& gyf) {
        const float4 z4 = make_float4(0.f, 0.f, 0.f, 0.f);
        float4 mU = z4, mC = z4, mD = z4, fU = z4, fC = z4, fD = z4;
        if ((unsigned)zl < (unsigned)DIM) {
            const float* pm = M + (size_t)zl * PLANE + (size_t)y * DIM + xb;
            const float* pf = F + (size_t)zl * PLANE + (size_t)y * DIM + xb;
            mC = *(const float4*)pm;  fC = *(const float4*)pf;
            if (yUok) { mU = *(const float4*)(pm - DIM); fU = *(const float4*)(pf - DIM); }
            if (yDok) { mD = *(const float4*)(pm + DIM); fD = *(const float4*)(pf + DIM); }
        }
        // y-sums per element (zero-padded SAME)
        float4 Cm  = add3(mU, mC, mD);
        float4 Cf  = add3(fU, fC, fD);
        float4 Cmm = prod3(mU, mU, mC, mC, mD, mD);
        float4 Cff = prod3(fU, fU, fC, fC, fD, fD);
        float4 Cmf = prod3(mU, fU, mC, fC, mD, fD);
        // x-sums (2 shuffles each)
        Pm[slot]  = xsum3(Cm);
        Pf[slot]  = xsum3(Cf);
        Pmm[slot] = xsum3(Cmm);
        Pff[slot] = xsum3(Cff);
        Pmf[slot] = xsum3(Cmf);
        mc[slot] = mC; fc[slot] = fC;
        // in-plane gradients at plane zl (torch.gradient boundary rules)
        float mL = shlz(mC.w), mR = shrz(mC.x);
        float fL = shlz(fC.w), fR = shrz(fC.x);
        gxm = make_float4((threadIdx.x == 0)  ? (mC.y - mC.x) : 0.5f*(mC.y - mL),
                          0.5f*(mC.z - mC.x),
                          0.5f*(mC.w - mC.y),
                          (threadIdx.x == 63) ? (mC.w - mC.z) : 0.5f*(mR - mC.z));
        gxf = make_float4((threadIdx.x == 0)  ? (fC.y - fC.x) : 0.5f*(fC.y - fL),
                          0.5f*(fC.z - fC.x),
                          0.5f*(fC.w - fC.y),
                          (threadIdx.x == 63) ? (fC.w - fC.z) : 0.5f*(fR - fC.z));
        gym = (y == 0) ? sub4(mD, mC) : (y == DIM-1) ? sub4(mC, mU) : scl4(sub4(mD, mU), 0.5f);
        gyf = (y == 0) ? sub4(fD, fC) : (y == DIM-1) ? sub4(fC, fU) : scl4(sub4(fD, fU), 0.5f);
    };

    // prime ring: planes z0-1 (zero pad if z0==0) and z0
    { float4 d0, d1, d2, d3; ingest(0, z0 - 1, d0, d1, d2, d3); }
    ingest(1, z0, gxm_p, gym_p, gxf_p, gyf_p);

    #pragma unroll
    for (int s = 2; s < CHUNK_Z + 2; ++s) {
        const int i2 = s % 3, i1 = (s + 2) % 3, i0 = (s + 1) % 3;
        float4 gxm, gym, gxf, gyf;
        ingest(i2, z0 - 1 + s, gxm, gym, gxf, gyf);

        const int zo = z0 + s - 2;
        const int zflag = (zo == 0) ? -1 : ((zo == DIM - 1) ? 1 : 0);
        const size_t idx = (size_t)zo * PLANE + (size_t)y * DIM + xb;

        int4 km = *(const int4*)(maskM + idx);
        int4 kf = *(const int4*)(maskF + idx);

        float4 sm  = add3(Pm[i0],  Pm[i1],  Pm[i2]);
        float4 sf  = add3(Pf[i0],  Pf[i1],  Pf[i2]);
        float4 smm = add3(Pmm[i0], Pmm[i1], Pmm[i2]);
        float4 sff = add3(Pff[i0], Pff[i1], Pff[i2]);
        float4 smf = add3(Pmf[i0], Pmf[i1], Pmf[i2]);

        float4 o0, o1, o2;
        pw1(sm.x, sf.x, smm.x, sff.x, smf.x, mc[i0].x, mc[i1].x, mc[i2].x,
            fc[i0].x, fc[i1].x, fc[i2].x, zflag, gxm_p.x, gym_p.x, gxf_p.x, gyf_p.x,
            km.x, kf.x, o0.x, o1.x, o2.x);
        pw1(sm.y, sf.y, smm.y, sff.y, smf.y, mc[i0].y, mc[i1].y, mc[i2].y,
            fc[i0].y, fc[i1].y, fc[i2].y, zflag, gxm_p.y, gym_p.y, gxf_p.y, gyf_p.y,
            km.y, kf.y, o0.y, o1.y, o2.y);
        pw1(sm.z, sf.z, smm.z, sff.z, smf.z, mc[i0].z, mc[i1].z, mc[i2].z,
            fc[i0].z, fc[i1].z, fc[i2].z, zflag, gxm_p.z, gym_p.z, gxf_p.z, gyf_p.z,
            km.z, kf.z, o0.z, o1.z, o2.z);
        pw1(sm.w, sf.w, smm.w, sff.w, smf.w, mc[i0].w, mc[i1].w, mc[i2].w,
            fc[i0].w, fc[i1].w, fc[i2].w, zflag, gxm_p.w, gym_p.w, gxf_p.w, gyf_p.w,
            km.w, kf.w, o0.w, o1.w, o2.w);

        ntstore4(out + idx,            o0);   // channel 0: d/dz
        ntstore4(out + NVOX + idx,     o1);   // channel 1: d/dy
        ntstore4(out + 2 * NVOX + idx, o2);   // channel 2: d/dx

        gxm_p = gxm; gym_p = gym; gxf_p = gxf; gyf_p = gyf;
    }
}

extern "C" void kernel_launch(void* const* d_in, const int* in_sizes, int n_in,
                              void* d_out, int out_size, void* d_ws, size_t ws_size,
                              hipStream_t stream) {
    const float* M  = (const float*)d_in[0];
    const float* F  = (const float*)d_in[1];
    const int* mm   = (const int*)d_in[2];
    const int* fm   = (const int*)d_in[3];
    float* out      = (float*)d_out;

    dim3 block(64, BY, 1);                       // one wave = one full x-row
    dim3 grid(1, DIM / BY, DIM / CHUNK_Z);       // 1 x 64 x 16 = 1024 blocks
    hipLaunchKernelGGL(ncc_forces, grid, block, 0, stream, M, F, mm, fm, out);
}

// Round 4
// 378.280 us; speedup vs baseline: 1.2300x; 1.0688x over previous
//
#include <hip/hip_runtime.h>

// NCC dual-force 3D, 256^3 fp32.
// One wave spans the FULL x-row: 64 lanes x 4 floats (float4) = 256.
// Separable 3x3x3 box sums: y-sum in registers, x-sum via 2 shuffles per
// quantity, z-sum via a 3-deep register ring (compile-time rotation under
// full unroll). 4 outputs per lane per plane-step. No LDS, no syncthreads.
// R4: CHUNK_Z=8, BY=2 (4096 blocks) to fix the R3 latency bound (occupancy
// 21%, both pipes <35%); NT mask loads; R1-exact epilogue ordering.

constexpr int DIM     = 256;
constexpr int PLANE   = DIM * DIM;
constexpr int NVOX    = DIM * DIM * DIM;
constexpr int CHUNK_Z = 8;             // outputs per thread along z
constexpr int BY      = 2;             // waves per block (y rows)
constexpr float EPSF  = 1e-6f;

// native vector types for nontemporal builtins (HIP_vector_type is rejected)
typedef float nvec4 __attribute__((ext_vector_type(4)));
typedef int   nivec4 __attribute__((ext_vector_type(4)));

__device__ __forceinline__ float shlz(float v) {   // lane l <- lane l-1; lane0 -> 0 (zero pad)
    float r = __shfl_up(v, 1);
    return (threadIdx.x == 0) ? 0.f : r;
}
__device__ __forceinline__ float shrz(float v) {   // lane l <- lane l+1; lane63 -> 0
    float r = __shfl_down(v, 1);
    return (threadIdx.x == 63) ? 0.f : r;
}
__device__ __forceinline__ float4 add3(const float4& a, const float4& b, const float4& c) {
    return make_float4(a.x+b.x+c.x, a.y+b.y+c.y, a.z+b.z+c.z, a.w+b.w+c.w);
}
__device__ __forceinline__ float4 prod3(const float4& a, const float4& b,
                                        const float4& c, const float4& d,
                                        const float4& e, const float4& f) {
    return make_float4(a.x*b.x + c.x*d.x + e.x*f.x,
                       a.y*b.y + c.y*d.y + e.y*f.y,
                       a.z*b.z + c.z*d.z + e.z*f.z,
                       a.w*b.w + c.w*d.w + e.w*f.w);
}
__device__ __forceinline__ float4 sub4(const float4& a, const float4& b) {
    return make_float4(a.x-b.x, a.y-b.y, a.z-b.z, a.w-b.w);
}
__device__ __forceinline__ float4 scl4(const float4& a, float s) {
    return make_float4(a.x*s, a.y*s, a.z*s, a.w*s);
}
// 3-wide x window sum of a per-element quantity; ends from neighbor lanes (zero-padded)
__device__ __forceinline__ float4 xsum3(const float4& c) {
    float l = shlz(c.w), r = shrz(c.x);
    return make_float4(l + c.x + c.y, c.x + c.y + c.z, c.y + c.z + c.w, c.z + c.w + r);
}
__device__ __forceinline__ void ntstore4(float* p, const float4& v) {
    nvec4 t; t.x = v.x; t.y = v.y; t.z = v.z; t.w = v.w;
    __builtin_nontemporal_store(t, (nvec4*)p);
}

// scalar pointwise NCC-force; arithmetic replicates the reference (and the
// R1 kernel, absmax 56) op-for-op — do NOT reorder, eps-denominator voxels
// are hyper-sensitive (R3's nf=-0.5*factor refactor cost absmax 56->80).
__device__ __forceinline__ void pw1(
    float sum_m, float sum_f, float sum_mm, float sum_ff, float sum_mf,
    float mA, float mB, float mN,   // m at planes zo-1, zo, zo+1
    float fA, float fB, float fN,
    int zflag,                      // -1: zo==0, +1: zo==DIM-1, 0: interior
    float gx_m, float gy_m, float gx_f, float gy_f,
    int km, int kf,
    float& o0, float& o1, float& o2)
{
    float mmean = sum_m / 27.0f;
    float fmean = sum_f / 27.0f;
    float var_m = sum_mm - 2.f*mmean*sum_m + 27.f*mmean*mmean;
    float var_f = sum_ff - 2.f*fmean*sum_f + 27.f*fmean*fmean;
    float var_mf = var_m * var_f;
    float cross = sum_mf - fmean*sum_m - mmean*sum_f + 27.f*mmean*fmean;
    float mmc = mB - mmean, fmc = fB - fmean;
    float factor = 2.f * cross / (var_mf + EPSF)
                   * (mmc - cross / (var_f*fmc + EPSF));
    float gzm = (zflag < 0) ? (mN - mB) : ((zflag > 0) ? (mB - mA) : 0.5f*(mN - mA));
    float gzf = (zflag < 0) ? (fN - fB) : ((zflag > 0) ? (fB - fA) : 0.5f*(fN - fA));
    float wm = km ? 1.f : 0.f, wf = kf ? 1.f : 0.f;
    float tgz = 0.5f*(gzm *wm + gzf *wf);
    float tgy = 0.5f*(gy_m*wm + gy_f*wf);
    float tgx = 0.5f*(gx_m*wm + gx_f*wf);
    o0 = -factor * tgz;
    o1 = -factor * tgy;
    o2 = -factor * tgx;
}

__global__ __launch_bounds__(64 * BY) void ncc_forces(
    const float* __restrict__ M, const float* __restrict__ F,
    const int* __restrict__ maskM, const int* __restrict__ maskF,
    float* __restrict__ out)
{
    const int y  = blockIdx.y * BY + threadIdx.y;
    const int z0 = blockIdx.z * CHUNK_Z;
    const int xb = threadIdx.x * 4;
    const bool yUok = (y > 0), yDok = (y < DIM - 1);

    float4 Pm[3], Pf[3], Pmm[3], Pff[3], Pmf[3];   // plane-sum z-ring
    float4 mc[3], fc[3];                           // center values z-ring
    float4 gxm_p, gym_p, gxf_p, gyf_p;             // in-plane grads at plane zo

    auto ingest = [&](int slot, int zl, float4& gxm, float4& gym, float4& gxf, float4& gyf) {
        const float4 z4 = make_float4(0.f, 0.f, 0.f, 0.f);
        float4 mU = z4, mC = z4, mD = z4, fU = z4, fC = z4, fD = z4;
        if ((unsigned)zl < (unsigned)DIM) {
            const float* pm = M + (size_t)zl * PLANE + (size_t)y * DIM + xb;
            const float* pf = F + (size_t)zl * PLANE + (size_t)y * DIM + xb;
            mC = *(const float4*)pm;  fC = *(const float4*)pf;
            if (yUok) { mU = *(const float4*)(pm - DIM); fU = *(const float4*)(pf - DIM); }
            if (yDok) { mD = *(const float4*)(pm + DIM); fD = *(const float4*)(pf + DIM); }
        }
        // y-sums per element (zero-padded SAME)
        float4 Cm  = add3(mU, mC, mD);
        float4 Cf  = add3(fU, fC, fD);
        float4 Cmm = prod3(mU, mU, mC, mC, mD, mD);
        float4 Cff = prod3(fU, fU, fC, fC, fD, fD);
        float4 Cmf = prod3(mU, fU, mC, fC, mD, fD);
        // x-sums (2 shuffles each)
        Pm[slot]  = xsum3(Cm);
        Pf[slot]  = xsum3(Cf);
        Pmm[slot] = xsum3(Cmm);
        Pff[slot] = xsum3(Cff);
        Pmf[slot] = xsum3(Cmf);
        mc[slot] = mC; fc[slot] = fC;
        // in-plane gradients at plane zl (torch.gradient boundary rules)
        float mL = shlz(mC.w), mR = shrz(mC.x);
        float fL = shlz(fC.w), fR = shrz(fC.x);
        gxm = make_float4((threadIdx.x == 0)  ? (mC.y - mC.x) : 0.5f*(mC.y - mL),
                          0.5f*(mC.z - mC.x),
                          0.5f*(mC.w - mC.y),
                          (threadIdx.x == 63) ? (mC.w - mC.z) : 0.5f*(mR - mC.z));
        gxf = make_float4((threadIdx.x == 0)  ? (fC.y - fC.x) : 0.5f*(fC.y - fL),
                          0.5f*(fC.z - fC.x),
                          0.5f*(fC.w - fC.y),
                          (threadIdx.x == 63) ? (fC.w - fC.z) : 0.5f*(fR - fC.z));
        gym = (y == 0) ? sub4(mD, mC) : (y == DIM-1) ? sub4(mC, mU) : scl4(sub4(mD, mU), 0.5f);
        gyf = (y == 0) ? sub4(fD, fC) : (y == DIM-1) ? sub4(fC, fU) : scl4(sub4(fD, fU), 0.5f);
    };

    // prime ring: planes z0-1 (zero pad if z0==0) and z0
    { float4 d0, d1, d2, d3; ingest(0, z0 - 1, d0, d1, d2, d3); }
    ingest(1, z0, gxm_p, gym_p, gxf_p, gyf_p);

    #pragma unroll
    for (int s = 2; s < CHUNK_Z + 2; ++s) {
        const int i2 = s % 3, i1 = (s + 2) % 3, i0 = (s + 1) % 3;
        float4 gxm, gym, gxf, gyf;
        ingest(i2, z0 - 1 + s, gxm, gym, gxf, gyf);

        const int zo = z0 + s - 2;
        const int zflag = (zo == 0) ? -1 : ((zo == DIM - 1) ? 1 : 0);
        const size_t idx = (size_t)zo * PLANE + (size_t)y * DIM + xb;

        // masks are single-use: nontemporal to spare L2 for reused image rows
        nivec4 km = __builtin_nontemporal_load((const nivec4*)(maskM + idx));
        nivec4 kf = __builtin_nontemporal_load((const nivec4*)(maskF + idx));

        float4 sm  = add3(Pm[i0],  Pm[i1],  Pm[i2]);
        float4 sf  = add3(Pf[i0],  Pf[i1],  Pf[i2]);
        float4 smm = add3(Pmm[i0], Pmm[i1], Pmm[i2]);
        float4 sff = add3(Pff[i0], Pff[i1], Pff[i2]);
        float4 smf = add3(Pmf[i0], Pmf[i1], Pmf[i2]);

        float4 o0, o1, o2;
        pw1(sm.x, sf.x, smm.x, sff.x, smf.x, mc[i0].x, mc[i1].x, mc[i2].x,
            fc[i0].x, fc[i1].x, fc[i2].x, zflag, gxm_p.x, gym_p.x, gxf_p.x, gyf_p.x,
            km.x, kf.x, o0.x, o1.x, o2.x);
        pw1(sm.y, sf.y, smm.y, sff.y, smf.y, mc[i0].y, mc[i1].y, mc[i2].y,
            fc[i0].y, fc[i1].y, fc[i2].y, zflag, gxm_p.y, gym_p.y, gxf_p.y, gyf_p.y,
            km.y, kf.y, o0.y, o1.y, o2.y);
        pw1(sm.z, sf.z, smm.z, sff.z, smf.z, mc[i0].z, mc[i1].z, mc[i2].z,
            fc[i0].z, fc[i1].z, fc[i2].z, zflag, gxm_p.z, gym_p.z, gxf_p.z, gyf_p.z,
            km.z, kf.z, o0.z, o1.z, o2.z);
        pw1(sm.w, sf.w, smm.w, sff.w, smf.w, mc[i0].w, mc[i1].w, mc[i2].w,
            fc[i0].w, fc[i1].w, fc[i2].w, zflag, gxm_p.w, gym_p.w, gxf_p.w, gyf_p.w,
            km.w, kf.w, o0.w, o1.w, o2.w);

        ntstore4(out + idx,            o0);   // channel 0: d/dz
        ntstore4(out + NVOX + idx,     o1);   // channel 1: d/dy
        ntstore4(out + 2 * NVOX + idx, o2);   // channel 2: d/dx

        gxm_p = gxm; gym_p = gym; gxf_p = gxf; gyf_p = gyf;
    }
}

extern "C" void kernel_launch(void* const* d_in, const int* in_sizes, int n_in,
                              void* d_out, int out_size, void* d_ws, size_t ws_size,
                              hipStream_t stream) {
    const float* M  = (const float*)d_in[0];
    const float* F  = (const float*)d_in[1];
    const int* mm   = (const int*)d_in[2];
    const int* fm   = (const int*)d_in[3];
    float* out      = (float*)d_out;

    dim3 block(64, BY, 1);                       // one wave = one full x-row
    dim3 grid(1, DIM / BY, DIM / CHUNK_Z);       // 1 x 128 x 32 = 4096 blocks
    hipLaunchKernelGGL(ncc_forces, grid, block, 0, stream, M, F, mm, fm, out);
}